// Round 1
// baseline (739.124 us; speedup 1.0000x reference)
//
#include <hip/hip_runtime.h>
#include <hip/hip_bf16.h>
#include <stdint.h>

// Problem: score [2,16,2048,2048] fp32, value [2,16,2048,128] fp32
// out[bh] = (fq(score) . fq(value)) * qs*ks  -- integer-valued matmul, exact in bf16 MFMA
#define S_DIM 2048
#define D_DIM 128
#define BH_N  32
#define BM    64
#define BK    64
#define NITER (S_DIM / BK)   // 32
#define ASTR  72             // (kernel 1 only) padded k-stride for transpose tile

typedef float  f32x4  __attribute__((ext_vector_type(4)));
typedef unsigned int u32x2 __attribute__((ext_vector_type(2)));
typedef unsigned int u32x4 __attribute__((ext_vector_type(4)));
typedef short  bf16x8 __attribute__((ext_vector_type(8)));

// fake_quant one float -> integer-valued bf16 (exact: |q| <= 129 < 256)
__device__ __forceinline__ unsigned short quant1(float v, float inv) {
    float q = rintf(v * inv);              // v_rndne_f32 == jnp.round (RNE)
    q = fminf(fmaxf(q, -129.0f), 127.0f);  // faithful MIN_INT = -129
    return (unsigned short)(__float_as_uint(q) >> 16);  // exact bf16 truncation
}

__device__ __forceinline__ bf16x8 quant8(f32x4 a, f32x4 b, float inv) {
    bf16x8 r;
    r[0] = (short)quant1(a.x, inv);
    r[1] = (short)quant1(a.y, inv);
    r[2] = (short)quant1(a.z, inv);
    r[3] = (short)quant1(a.w, inv);
    r[4] = (short)quant1(b.x, inv);
    r[5] = (short)quant1(b.y, inv);
    r[6] = (short)quant1(b.z, inv);
    r[7] = (short)quant1(b.w, inv);
    return r;
}

// ---------------------------------------------------------------------------
// Kernel 1: quantize value and transpose to vt[bh][d][k] (bf16, k-contiguous)
// (unchanged — ~15 us, not on the critical path)
// ---------------------------------------------------------------------------
__global__ __launch_bounds__(256) void vt_quant_kernel(
        const float* __restrict__ value,
        const float* __restrict__ ks_p,
        unsigned short* __restrict__ vt) {
    __shared__ unsigned short T[D_DIM * ASTR];  // [d][k] padded

    const int bid = blockIdx.x;
    const int bh  = bid >> 5;
    const int k0  = (bid & 31) * BK;
    const float inv = 1.0f / ks_p[0];
    const int tid = threadIdx.x;

    const float* src = value + ((size_t)bh * S_DIM + k0) * D_DIM;

#pragma unroll
    for (int i = 0; i < 8; ++i) {
        int f  = tid + 256 * i;         // 0..2047 float4s of the 64x128 tile
        int k  = f >> 5;                // 0..63
        int c4 = (f & 31) * 4;          // d base 0..124
        f32x4 v = *(const f32x4*)(src + (size_t)k * D_DIM + c4);
        T[(c4 + 0) * ASTR + k] = quant1(v.x, inv);
        T[(c4 + 1) * ASTR + k] = quant1(v.y, inv);
        T[(c4 + 2) * ASTR + k] = quant1(v.z, inv);
        T[(c4 + 3) * ASTR + k] = quant1(v.w, inv);
    }
    __syncthreads();

    unsigned short* dst = vt + (size_t)bh * D_DIM * S_DIM + k0;
#pragma unroll
    for (int i = 0; i < 4; ++i) {
        int c = tid + 256 * i;          // 0..1023 16B-chunks (128 d x 8 chunks)
        int n = c >> 3;                 // d row 0..127
        int q = (c & 7) * 8;            // k offset within tile
        u32x4 x = *(const u32x4*)(&T[n * ASTR + q]);
        *(u32x4*)(dst + (size_t)n * S_DIM + q) = x;
    }
}

// ---------------------------------------------------------------------------
// Kernel 2 (restructured): fused quantize(score) + bf16 MFMA GEMM.
// 1024 blocks = 256 CU x 4 (all resident, no tail), 256 thr = 4 waves.
// Each wave owns 16 M-rows x full D=128; A-fragments load DIRECTLY from
// global into registers (16 rows x 128B = 16 full cache lines / inst),
// quantized in-register -- no A LDS round-trip.
// B double-buffered in LDS via global_load_lds; 2-phase pipeline with
// counted s_waitcnt vmcnt(8) (never drains to 0 in steady state) and raw
// s_barrier, so 8 VMEM ops (next tile) stay in flight across every barrier.
// XCD-aware decode clusters each bh onto one XCD: vt working set per XCD
// drops 16 MB -> 2 MB (< 4 MB L2), killing vt HBM re-fetch.
// ---------------------------------------------------------------------------
__global__ __launch_bounds__(256, 4) void bmm_kernel(
        const float* __restrict__ score,
        const unsigned short* __restrict__ vt,
        const float* __restrict__ qs_p,
        const float* __restrict__ ks_p,
        float* __restrict__ out) {
    __shared__ unsigned short Bs[2][D_DIM * BK];   // 2 x 16 KB

    // XCD-aware decode (dispatch is round-robin: xcd = bid & 7).
    // Each XCD gets bh in [xcd*4, xcd*4+4) -> vt L2-resident per XCD.
    const int bid = blockIdx.x;
    const int xcd = bid & 7;
    const int idx = bid >> 3;                  // 0..127
    const int bh  = xcd * 4 + (idx >> 5);      // 4 bh per XCD
    const int m0  = (idx & 31) * BM;

    const float qs     = qs_p[0];
    const float inv_qs = 1.0f / qs;
    const float fin    = qs * ks_p[0];

    const int tid  = threadIdx.x;
    const int lane = tid & 63;
    const int wave = tid >> 6;
    const int m16  = lane & 15;
    const int quad = lane >> 4;

    // Per-lane A row pointer: row = m0 + wave*16 + m16, k-base quad*8.
    const float* Aptr = score + (size_t)bh * S_DIM * S_DIM
                      + (size_t)(m0 + wave * 16 + m16) * S_DIM + quad * 8;
    const unsigned short* Bt = vt + (size_t)bh * D_DIM * S_DIM;

    f32x4 acc[8] = {};          // 8 n-fragments (n = j*16 + m16), 32 VGPR
    f32x4 ra0[4], ra1[4];       // A double-buffer: 2 x (2 kk-substeps x 16B)

    // ---- B stage: 16 KB tile, 4 global_load_lds dwordx4 / thread,
    //      chunk-XOR swizzle pre-applied on the GLOBAL source (LDS linear).
#define STAGE_B(BUF, KB)                                                      \
    _Pragma("unroll")                                                         \
    for (int i = 0; i < 4; ++i) {                                             \
        int p  = i * 256 + tid;          /* 16B chunk 0..1023 */              \
        int n  = p >> 3;                 /* d row */                          \
        int ql = (p & 7) ^ (n & 7);      /* XOR swizzle on k-chunk */         \
        __builtin_amdgcn_global_load_lds(                                     \
            (const __attribute__((address_space(1))) void*)                  \
                (Bt + (size_t)n * S_DIM + (KB) + ql * 8),                     \
            (__attribute__((address_space(3))) void*)(&Bs[BUF][p * 8]),       \
            16, 0, 0);                                                        \
    }

    // ---- A loads: 32B per lane per kk-substep, nontemporal (score is
    //      streamed exactly once).
#define LOAD_A(R, KB)                                                         \
    R[0] = __builtin_nontemporal_load((const f32x4*)(Aptr + (KB)));           \
    R[1] = __builtin_nontemporal_load((const f32x4*)(Aptr + (KB) + 4));       \
    R[2] = __builtin_nontemporal_load((const f32x4*)(Aptr + (KB) + 32));      \
    R[3] = __builtin_nontemporal_load((const f32x4*)(Aptr + (KB) + 36));

    // ---- compute one 64-k tile: quant A in-register, 16 MFMA
#define COMPUTE(BUF, R) {                                                     \
    bf16x8 af0 = quant8(R[0], R[1], inv_qs);  /* kk = 0  */                   \
    bf16x8 af1 = quant8(R[2], R[3], inv_qs);  /* kk = 32 */                   \
    const int s8 = m16 & 7;                                                   \
    _Pragma("unroll")                                                         \
    for (int j = 0; j < 8; ++j) {                                             \
        bf16x8 b0 = *(const bf16x8*)(                                         \
            &Bs[BUF][((j * 16 + m16) * 8 + (quad ^ s8)) * 8]);                \
        acc[j] = __builtin_amdgcn_mfma_f32_16x16x32_bf16(af0, b0, acc[j],     \
                                                         0, 0, 0);            \
    }                                                                         \
    _Pragma("unroll")                                                         \
    for (int j = 0; j < 8; ++j) {                                             \
        bf16x8 b1 = *(const bf16x8*)(                                         \
            &Bs[BUF][((j * 16 + m16) * 8 + ((quad + 4) ^ s8)) * 8]);          \
        acc[j] = __builtin_amdgcn_mfma_f32_16x16x32_bf16(af1, b1, acc[j],     \
                                                         0, 0, 0);            \
    } }

    // ---- prologue: two tiles in flight (groups of 8 VMEM ops each)
    STAGE_B(0, 0)
    LOAD_A(ra0, 0)
    STAGE_B(1, BK)
    LOAD_A(ra1, BK)

    // ---- steady state: wait vmcnt(8) completes the oldest group (this
    //      tile's 4 B-lds + 4 A loads) while the next group stays in flight.
    //      Raw s_barrier (NOT __syncthreads) so the compiler doesn't drain.
    for (int t = 0; t < NITER - 2; t += 2) {
        asm volatile("s_waitcnt vmcnt(8)" ::: "memory");
        __builtin_amdgcn_s_barrier();
        COMPUTE(0, ra0)
        __builtin_amdgcn_s_barrier();          // all reads of Bs[0] done (WAR)
        STAGE_B(0, (t + 2) * BK)
        LOAD_A(ra0, (t + 2) * BK)

        asm volatile("s_waitcnt vmcnt(8)" ::: "memory");
        __builtin_amdgcn_s_barrier();
        COMPUTE(1, ra1)
        __builtin_amdgcn_s_barrier();          // all reads of Bs[1] done (WAR)
        STAGE_B(1, (t + 3) * BK)
        LOAD_A(ra1, (t + 3) * BK)
    }
    // ---- epilogue tiles 30, 31 (no restage; drain only at the very end)
    asm volatile("s_waitcnt vmcnt(8)" ::: "memory");
    __builtin_amdgcn_s_barrier();
    COMPUTE(0, ra0)
    asm volatile("s_waitcnt vmcnt(0)" ::: "memory");
    __builtin_amdgcn_s_barrier();
    COMPUTE(1, ra1)

    // ---- C write: C/D layout col=lane&15, row=quad*4+reg
    float* O = out + (size_t)bh * S_DIM * D_DIM
             + (size_t)(m0 + wave * 16 + quad * 4) * D_DIM + m16;
#pragma unroll
    for (int j = 0; j < 8; ++j)
#pragma unroll
        for (int r = 0; r < 4; ++r)
            O[(size_t)r * D_DIM + j * 16] = acc[j][r] * fin;

#undef STAGE_B
#undef LOAD_A
#undef COMPUTE
}

extern "C" void kernel_launch(void* const* d_in, const int* in_sizes, int n_in,
                              void* d_out, int out_size, void* d_ws, size_t ws_size,
                              hipStream_t stream) {
    const float* score = (const float*)d_in[0];
    const float* value = (const float*)d_in[1];
    const float* qs    = (const float*)d_in[2];
    const float* ks    = (const float*)d_in[3];
    float* out = (float*)d_out;
    unsigned short* vt = (unsigned short*)d_ws;  // 32*128*2048*2 = 16 MiB

    vt_quant_kernel<<<BH_N * (S_DIM / BK), 256, 0, stream>>>(value, ks, vt);
    bmm_kernel<<<BH_N * (S_DIM / BM), 256, 0, stream>>>(score, vt, qs, ks, out);
}